// Round 9
// baseline (41.312 us; speedup 1.0000x reference)
//
#include <hip/hip_runtime.h>

#define BATCH 4
#define NROWS 2048
#define IN_DIM 1024
#define OUT_DIM 512
#define DSPLIT 16           // w2part slices
#define NPROD 32            // producer blocks (2 per slice)
#define NCHUNK 256          // chunks total (64 per batch)
#define RPB 32              // rows per chunk

#define LD_ACQ(p)    __hip_atomic_load((p), __ATOMIC_ACQUIRE, __HIP_MEMORY_SCOPE_AGENT)
#define ADD_REL(p,v) __hip_atomic_fetch_add((p), (v), __ATOMIC_RELEASE, __HIP_MEMORY_SCOPE_AGENT)

// ---- D1: w2 production (32 blocks) + flash chunk pass, one dispatch ----
// All 256 blocks co-resident (1/CU): producers write w2part (normal stores)
// then release-add a counter; every block first ISSUES its 16 x-row loads
// (HBM streams during the wait), then acquire-spins, merges w2, computes
// e=exp(x.w2) and the weighted partials. x is read exactly once.
__global__ void __launch_bounds__(512)
d1_fused(const float* __restrict__ x,
         const float* __restrict__ fc_w,
         const float* __restrict__ attn_w,
         unsigned int* __restrict__ w2cnt,
         float* __restrict__ w2part,
         float* __restrict__ yu,
         float* __restrict__ Zc)
{
    const int bid = blockIdx.x, t = threadIdx.x;
    const int w = t >> 6, lane = t & 63;
    __shared__ float w2s[IN_DIM];                 // 4 KB
    __shared__ float4 sbuf[8 * 256];              // 32 KB
    __shared__ float zbuf[8];

    // ---- producers: slice ds = bid>>1, col-half = bid&1 ----
    if (bid < NPROD) {
        const int ds = bid >> 1;
        const int col = ((bid & 1) << 9) + t;
        const int d0 = ds << 5;
        float acc = 0.f;
#pragma unroll 8
        for (int j = 0; j < 32; ++j)
            acc += fc_w[(size_t)(d0 + j) * IN_DIM + col] * attn_w[OUT_DIM + d0 + j];
        w2part[(ds << 10) + col] = acc;           // normal store (stays in L2)
        __syncthreads();                          // stores drained to L2
        if (t == 0) ADD_REL(w2cnt, 1u);           // release: L2 writeback, then add
    }

    // ---- all blocks: issue own 32 x-rows into registers (4/wave-lane-set) ----
    const float4* x4 = (const float4*)x;
    const size_t row0 = (size_t)bid * RPB + (w << 2);
    float4 v0[4], v1[4], v2[4], v3[4];
#pragma unroll
    for (int r = 0; r < 4; ++r) {
        size_t base = (row0 + r) << 8;            // float4 units
        v0[r] = x4[base + lane];
        v1[r] = x4[base + lane + 64];
        v2[r] = x4[base + lane + 128];
        v3[r] = x4[base + lane + 192];
    }
    // pin the loads before the spin (issue-early)
#pragma unroll
    for (int r = 0; r < 4; ++r)
        asm volatile("" :: "v"(v0[r].x), "v"(v1[r].x), "v"(v2[r].x), "v"(v3[r].x));

    // ---- join: spin until all 32 producer blocks released ----
    if (t == 0) { while (LD_ACQ(w2cnt) < NPROD) __builtin_amdgcn_s_sleep(8); }
    __syncthreads();                              // acquire published to block

    // merge the 16 w2 slices into LDS (normal loads, post-acquire)
    if (t < 256) {
        const float4* wp = (const float4*)w2part;
        float4 s = {0.f, 0.f, 0.f, 0.f};
#pragma unroll
        for (int ds = 0; ds < DSPLIT; ++ds) {
            float4 q = wp[(ds << 8) + t];
            s.x += q.x; s.y += q.y; s.z += q.z; s.w += q.w;
        }
        ((float4*)w2s)[t] = s;
    }
    __syncthreads();

    // ---- chunk pass on register-held rows ----
    const float4* w2s4 = (const float4*)w2s;
    const float4 u0 = w2s4[lane],       u1 = w2s4[lane + 64],
                 u2 = w2s4[lane + 128], u3 = w2s4[lane + 192];
    float4 a0 = {0,0,0,0}, a1 = {0,0,0,0}, a2 = {0,0,0,0}, a3 = {0,0,0,0};
    float zw = 0.f;
#pragma unroll
    for (int r = 0; r < 4; ++r) {
        float d = v0[r].x*u0.x + v0[r].y*u0.y + v0[r].z*u0.z + v0[r].w*u0.w
                + v1[r].x*u1.x + v1[r].y*u1.y + v1[r].z*u1.z + v1[r].w*u1.w
                + v2[r].x*u2.x + v2[r].y*u2.y + v2[r].z*u2.z + v2[r].w*u2.w
                + v3[r].x*u3.x + v3[r].y*u3.y + v3[r].z*u3.z + v3[r].w*u3.w;
#pragma unroll
        for (int off = 32; off; off >>= 1) d += __shfl_xor(d, off, 64);
        float e = __expf(d);        // |s2| <~ 5: safe fp32; softmax max-term cancels exactly
        zw += e;
        a0.x += e*v0[r].x; a0.y += e*v0[r].y; a0.z += e*v0[r].z; a0.w += e*v0[r].w;
        a1.x += e*v1[r].x; a1.y += e*v1[r].y; a1.z += e*v1[r].z; a1.w += e*v1[r].w;
        a2.x += e*v2[r].x; a2.y += e*v2[r].y; a2.z += e*v2[r].z; a2.w += e*v2[r].w;
        a3.x += e*v3[r].x; a3.y += e*v3[r].y; a3.z += e*v3[r].z; a3.w += e*v3[r].w;
    }
    sbuf[(w << 8) + lane]       = a0;
    sbuf[(w << 8) + lane + 64]  = a1;
    sbuf[(w << 8) + lane + 128] = a2;
    sbuf[(w << 8) + lane + 192] = a3;
    if (lane == 0) zbuf[w] = zw;
    __syncthreads();

    if (t < 256) {
        float4 s = {0.f, 0.f, 0.f, 0.f};
#pragma unroll
        for (int i = 0; i < 8; ++i) {
            float4 q = sbuf[(i << 8) + t];
            s.x += q.x; s.y += q.y; s.z += q.z; s.w += q.w;
        }
        ((float4*)(yu + ((size_t)bid << 10)))[t] = s;
        if (t == 0) {
            float z = 0.f;
#pragma unroll
            for (int i = 0; i < 8; ++i) z += zbuf[i];
            Zc[bid] = z;
        }
    }
}

// ---- D2: y merge (redundant) + c slice + out tile write (R8 proven) ----
__global__ void __launch_bounds__(256)
k3_fused(const float* __restrict__ yu,
         const float* __restrict__ Zc,
         const float* __restrict__ fc_w,
         const float* __restrict__ fc_b,
         float4* __restrict__ out) {
    const int bid = blockIdx.x;
    const int b = bid >> 6, rem = bid & 63, ds = rem >> 2, rg = rem & 3;
    const int t = threadIdx.x, w = t >> 6, lane = t & 63;
    __shared__ float ys[IN_DIM];
    __shared__ float cs[32];
    __shared__ float zsh;

    if (w == 0) {
        float z = Zc[(b << 6) + lane];
#pragma unroll
        for (int off = 32; off; off >>= 1) z += __shfl_xor(z, off, 64);
        if (lane == 0) zsh = 1.f / z;
    }

    const float4* yu4 = (const float4*)yu + ((size_t)b << 14);
    float4 acc = {0.f, 0.f, 0.f, 0.f};
#pragma unroll 8
    for (int c = 0; c < 64; ++c) {
        float4 v = yu4[(c << 8) + t];
        acc.x += v.x; acc.y += v.y; acc.z += v.z; acc.w += v.w;
    }
    __syncthreads();
    const float invZ = zsh;
    acc.x *= invZ; acc.y *= invZ; acc.z *= invZ; acc.w *= invZ;
    ((float4*)ys)[t] = acc;
    __syncthreads();

    const float4* ys4 = (const float4*)ys;
    const float4 y0 = ys4[lane],       y1 = ys4[lane + 64],
                 y2 = ys4[lane + 128], y3 = ys4[lane + 192];
#pragma unroll
    for (int q = 0; q < 8; ++q) {
        int dl = (w << 3) + q;
        int d = (ds << 5) + dl;
        const float4* fr = (const float4*)fc_w + ((size_t)d << 8);
        float4 f0 = fr[lane], f1 = fr[lane + 64], f2 = fr[lane + 128], f3 = fr[lane + 192];
        float s = f0.x*y0.x + f0.y*y0.y + f0.z*y0.z + f0.w*y0.w
                + f1.x*y1.x + f1.y*y1.y + f1.z*y1.z + f1.w*y1.w
                + f2.x*y2.x + f2.y*y2.y + f2.z*y2.z + f2.w*y2.w
                + f3.x*y3.x + f3.y*y3.y + f3.z*y3.z + f3.w*y3.w;
#pragma unroll
        for (int off = 32; off; off >>= 1) s += __shfl_xor(s, off, 64);
        if (lane == 0) cs[dl] = s + fc_b[d];
    }
    __syncthreads();

    const float4 val = ((const float4*)cs)[t & 7];
    const int lr = t >> 3;
    size_t rowbase = ((size_t)b * NROWS + (rg << 9) + lr) * 128 + (ds << 3) + (t & 7);
#pragma unroll
    for (int it = 0; it < 16; ++it)
        out[rowbase + (size_t)it * 32 * 128] = val;
}

extern "C" void kernel_launch(void* const* d_in, const int* in_sizes, int n_in,
                              void* d_out, int out_size, void* d_ws, size_t ws_size,
                              hipStream_t stream) {
    const float* x      = (const float*)d_in[0];
    const float* fc_w   = (const float*)d_in[1];
    const float* fc_b   = (const float*)d_in[2];
    const float* attn_w = (const float*)d_in[3];
    // attn_b (d_in[4]) cancels in the softmax — unused.

    unsigned int* flags = (unsigned int*)d_ws;
    float* fbase  = (float*)(flags + 16);
    float* w2part = fbase;                          // 16384 floats
    float* Zc     = w2part + DSPLIT * IN_DIM;       // 256
    float* yu     = Zc + NCHUNK;                    // 262144
    float* out    = (float*)d_out;                  // ws total ~1.07 MB

    hipMemsetAsync(flags, 0, 64, stream);           // zero join counter each call
    d1_fused<<<NCHUNK, 512, 0, stream>>>(x, fc_w, attn_w, flags, w2part, yu, Zc);
    k3_fused<<<256,    256, 0, stream>>>(yu, Zc, fc_w, fc_b, (float4*)out);
}

// Round 10
// 29.023 us; speedup vs baseline: 1.4234x; 1.4234x over previous
//
#include <hip/hip_runtime.h>

#define BATCH 4
#define NROWS 2048
#define IN_DIM 1024
#define OUT_DIM 512
#define DSPLIT 16
#define NCHUNK 256          // chunks total (64 per batch)
#define RPB 32              // rows per chunk

typedef float f4 __attribute__((ext_vector_type(4)));

// ---- K1: w2part[ds][col] = sum_{d in slice} fc_w[d][col] * a2[d] ------
__global__ void __launch_bounds__(256)
k1_w2part(const float* __restrict__ fc_w,
          const float* __restrict__ attn_w,
          float* __restrict__ w2part) {
    int ds = blockIdx.x >> 2, cg = blockIdx.x & 3;   // 64 blocks
    int col = (cg << 8) + threadIdx.x;
    int d0 = ds << 5;
    float acc = 0.f;
#pragma unroll 8
    for (int j = 0; j < 32; ++j)
        acc += fc_w[(size_t)(d0 + j) * IN_DIM + col] * attn_w[OUT_DIM + d0 + j];
    w2part[(ds << 10) + col] = acc;
}

// ---- K2: per-chunk flash pass: yu_c = sum_r e^{s2_r} x_r, Zc = sum e --
// 256 blocks x 512 threads; 8 waves x 4 rows; x read ONCE (nontemporal).
__global__ void __launch_bounds__(512)
k2_chunk(const float* __restrict__ x,
         const float* __restrict__ w2part,
         float* __restrict__ yu,
         float* __restrict__ Zc) {
    const int bid = blockIdx.x, t = threadIdx.x;
    const int w = t >> 6, lane = t & 63;
    __shared__ float w2s[IN_DIM];                 // 4 KB
    __shared__ f4 sbuf[8 * 256];                  // 32 KB
    __shared__ float zbuf[8];

    if (t < 256) {
        const f4* wp = (const f4*)w2part;
        f4 s = {0.f, 0.f, 0.f, 0.f};
#pragma unroll
        for (int ds = 0; ds < DSPLIT; ++ds) s += wp[(ds << 8) + t];
        ((f4*)w2s)[t] = s;
    }
    __syncthreads();

    const f4* x4 = (const f4*)x;
    const f4* w2s4 = (const f4*)w2s;
    const f4 u0 = w2s4[lane],       u1 = w2s4[lane + 64],
             u2 = w2s4[lane + 128], u3 = w2s4[lane + 192];

    size_t row0 = (size_t)bid * RPB + (w << 2);
    f4 a0 = {0,0,0,0}, a1 = {0,0,0,0}, a2 = {0,0,0,0}, a3 = {0,0,0,0};
    float zw = 0.f;
#pragma unroll
    for (int r = 0; r < 4; ++r) {
        size_t base = (row0 + r) << 8;            // f4 units
        f4 v0 = __builtin_nontemporal_load(&x4[base + lane]);
        f4 v1 = __builtin_nontemporal_load(&x4[base + lane + 64]);
        f4 v2 = __builtin_nontemporal_load(&x4[base + lane + 128]);
        f4 v3 = __builtin_nontemporal_load(&x4[base + lane + 192]);
        f4 p = v0 * u0 + v1 * u1 + v2 * u2 + v3 * u3;
        float d = (p.x + p.y) + (p.z + p.w);
#pragma unroll
        for (int off = 32; off; off >>= 1) d += __shfl_xor(d, off, 64);
        float e = __expf(d);            // |s2| ~ 0.1: safe fp32; softmax max-term cancels exactly
        zw += e;
        a0 += e * v0; a1 += e * v1; a2 += e * v2; a3 += e * v3;
    }
    sbuf[(w << 8) + lane]       = a0;
    sbuf[(w << 8) + lane + 64]  = a1;
    sbuf[(w << 8) + lane + 128] = a2;
    sbuf[(w << 8) + lane + 192] = a3;
    if (lane == 0) zbuf[w] = zw;
    __syncthreads();

    // publish yu with all 512 threads (float2 granularity); stores stay cached (k3 re-reads)
    {
        const float2* sb2 = (const float2*)sbuf;      // 8 x 512 float2
        float2 s = {0.f, 0.f};
#pragma unroll
        for (int i = 0; i < 8; ++i) {
            float2 q = sb2[(i << 9) + t];
            s.x += q.x; s.y += q.y;
        }
        ((float2*)(yu + ((size_t)bid << 10)))[t] = s;
    }
    if (t == 0) {
        float z = 0.f;
#pragma unroll
        for (int i = 0; i < 8; ++i) z += zbuf[i];
        Zc[bid] = z;
    }
}

// ---- K3: y merge (redundant per block) + c slice ----------------------
// 128 blocks: (b, ds in [0,32)); each computes 16 c-values.
__global__ void __launch_bounds__(256)
k3_yc(const float* __restrict__ yu,
      const float* __restrict__ Zc,
      const float* __restrict__ fc_w,
      const float* __restrict__ fc_b,
      float* __restrict__ cb) {
    const int b = blockIdx.x >> 5, ds = blockIdx.x & 31;
    const int t = threadIdx.x, w = t >> 6, lane = t & 63;
    __shared__ float ys[IN_DIM];
    __shared__ float zsh;

    if (w == 0) {
        float z = Zc[(b << 6) + lane];
#pragma unroll
        for (int off = 32; off; off >>= 1) z += __shfl_xor(z, off, 64);
        if (lane == 0) zsh = 1.f / z;
    }

    const f4* yu4 = (const f4*)yu + ((size_t)b << 14);
    f4 acc = {0.f, 0.f, 0.f, 0.f};
#pragma unroll 8
    for (int c = 0; c < 64; ++c) acc += yu4[(c << 8) + t];
    __syncthreads();
    acc *= zsh;
    ((f4*)ys)[t] = acc;
    __syncthreads();

    const f4* ys4 = (const f4*)ys;
    const f4 y0 = ys4[lane],       y1 = ys4[lane + 64],
             y2 = ys4[lane + 128], y3 = ys4[lane + 192];
#pragma unroll
    for (int q = 0; q < 4; ++q) {
        int d = (ds << 4) + (w << 2) + q;
        const f4* fr = (const f4*)fc_w + ((size_t)d << 8);
        f4 p = fr[lane] * y0 + fr[lane + 64] * y1 + fr[lane + 128] * y2 + fr[lane + 192] * y3;
        float s = (p.x + p.y) + (p.z + p.w);
#pragma unroll
        for (int off = 32; off; off >>= 1) s += __shfl_xor(s, off, 64);
        if (lane == 0) cb[(b << 9) + d] = s + fc_b[d];
    }
}

// ---- K4: out[b,n,:] = c[b,:] broadcast; 2048 blocks x 4 rows ----------
__global__ void __launch_bounds__(256)
k4_bcast(const float* __restrict__ cb, f4* __restrict__ out) {
    const int bid = blockIdx.x, t = threadIdx.x;
    const int row0 = bid << 2;              // 4 rows per block
    const int b = row0 >> 11;
    __shared__ f4 cs[128];
    if (t < 128) cs[t] = ((const f4*)cb)[(b << 7) + t];
    __syncthreads();
    f4* o = out + ((size_t)row0 << 7);      // 512 f4 per block
    f4 v = cs[t & 127];
    __builtin_nontemporal_store(v, o + t);
    __builtin_nontemporal_store(v, o + t + 256);
}

extern "C" void kernel_launch(void* const* d_in, const int* in_sizes, int n_in,
                              void* d_out, int out_size, void* d_ws, size_t ws_size,
                              hipStream_t stream) {
    const float* x      = (const float*)d_in[0];
    const float* fc_w   = (const float*)d_in[1];
    const float* fc_b   = (const float*)d_in[2];
    const float* attn_w = (const float*)d_in[3];
    // attn_b (d_in[4]) cancels in the softmax — unused.

    float* wsf    = (float*)d_ws;
    float* w2part = wsf;                               // 16384
    float* Zc     = w2part + DSPLIT * IN_DIM;          // 256
    float* yu     = Zc + NCHUNK;                       // 262144
    float* cb     = yu + (size_t)NCHUNK * IN_DIM;      // 2048
    float* out    = (float*)d_out;                     // ws total ~1.12 MB

    k1_w2part<<<64,     256, 0, stream>>>(fc_w, attn_w, w2part);
    k2_chunk <<<NCHUNK, 512, 0, stream>>>(x, w2part, yu, Zc);
    k3_yc    <<<128,    256, 0, stream>>>(yu, Zc, fc_w, fc_b, cb);
    k4_bcast <<<2048,   256, 0, stream>>>(cb, (f4*)out);
}